// Round 2
// baseline (584.799 us; speedup 1.0000x reference)
//
#include <hip/hip_runtime.h>
#include <hip/hip_bf16.h>
#include <math.h>

#define BB 4
#define CC 64
#define HH 160
#define WW 160
#define HWs (HH*WW)        // 25600
#define NPIX (BB*HWs)      // 102400

using bf16 = __hip_bfloat16;
__device__ __forceinline__ float bf2f(bf16 v){ return __bfloat162float(v); }
__device__ __forceinline__ bf16 f2bf(float v){ return __float2bfloat16(v); }

// ---- workspace layout (float offsets) ----
constexpr int AMAP = 0;                    // NPIX  : 1 + sigmoid(attn+edge)
constexpr int W1X1 = AMAP + NPIX;          // 4096  : fused dyn1d 1x1 weights, layout [c][o]
constexpr int B1X1 = W1X1 + 4096;          // 64    : summed dyn1d biases
constexpr int SFWt = B1X1 + 64;            // 36864 : BN-scaled sf weights, [og][ic][j][o16]
constexpr int SFBo = SFWt + 36864;         // 64    : BN-folded sf bias
constexpr int BAWt = SFBo + 64;            // 18432 : ba_w1 transposed [ic][j][o32]
constexpr int FCWt = BAWt + 18432;         // 4096  : fc_w transposed [c][o]
constexpr int WS_FLOATS = FCWt + 4096;     // 166016 floats = 664,064 B
// bf16 region after that: FUS, Y1 each BB*CC*HWs = 6,553,600 elems (13.1 MB each)

// ================= K0: weight prep (folds + transposes), all fp32 =================
__global__ void k_prep(const float* __restrict__ rk5w, const float* __restrict__ rk5b,
                       const float* __restrict__ rk7w, const float* __restrict__ rk7b,
                       const float* __restrict__ lk5w, const float* __restrict__ lk5b,
                       const float* __restrict__ lk7w, const float* __restrict__ lk7b,
                       const float* __restrict__ sfw,  const float* __restrict__ sfb,
                       const float* __restrict__ bng,  const float* __restrict__ bnb,
                       const float* __restrict__ bnm,  const float* __restrict__ bnv,
                       const float* __restrict__ baw1, const float* __restrict__ fcw,
                       float* __restrict__ ws)
{
    int tid = blockIdx.x*blockDim.x + threadIdx.x;
    int nt  = gridDim.x*blockDim.x;
    // fused dyn1d 1x1 weights: W[c][o] = sum_k kw[(oo*K+k)*64 + c]
    for(int idx=tid; idx<4096; idx+=nt){
        int c = idx>>6, o = idx&63;
        int grp = o>>4, oo = o&15;
        int K = (grp&1)?7:5;
        const float* w = (grp==0)?rk5w:(grp==1)?rk7w:(grp==2)?lk5w:lk7w;
        float s = 0.f;
        for(int k=0;k<K;k++) s += w[(oo*K+k)*64 + c];
        ws[W1X1 + c*64 + o] = s;
    }
    for(int o=tid;o<64;o+=nt){
        int grp=o>>4, oo=o&15; int K=(grp&1)?7:5;
        const float* bp = (grp==0)?rk5b:(grp==1)?rk7b:(grp==2)?lk5b:lk7b;
        float s=0.f; for(int k=0;k<K;k++) s += bp[oo*K+k];
        ws[B1X1+o]=s;
    }
    // sf conv, BN scale folded into weights, transposed to [og][ic][j][o16]
    for(int idx=tid; idx<36864; idx+=nt){
        int o  = idx & 15;
        int j  = (idx>>4) % 9;
        int ic = (idx/144) & 63;
        int og = idx/(144*64);
        int oc = og*16 + o;
        float sc = bng[oc]*rsqrtf(bnv[oc]+1e-5f);
        ws[SFWt+idx] = sfw[(oc*64 + ic)*9 + j] * sc;
    }
    for(int oc=tid;oc<64;oc+=nt){
        float sc = bng[oc]*rsqrtf(bnv[oc]+1e-5f);
        ws[SFBo+oc] = sfb[oc]*sc + bnb[oc] - bnm[oc]*sc;
    }
    // ba_w1 transposed to [ic][j][o32]
    for(int idx=tid; idx<18432; idx+=nt){
        int o  = idx & 31;
        int j  = (idx>>5) % 9;
        int ic = idx/288;
        ws[BAWt+idx] = baw1[(o*64 + ic)*9 + j];
    }
    // fc_w transposed to [c][o]
    for(int idx=tid; idx<4096; idx+=nt){
        int o = idx & 63, c = idx>>6;
        ws[FCWt+idx] = fcw[o*64 + c];
    }
}

// ============ K1: fused sobel-edge + attention convs -> AMAP = 1 + sigmoid ============
// 8x8 pixel tile per 64-thread block; LDS holds 10x10 halo tile of all 64 channels.
__global__ __launch_bounds__(64)
void k_attn(const float* __restrict__ x, const float* __restrict__ bab1,
            const float* __restrict__ baw2, const float* __restrict__ bab2,
            const float* __restrict__ ws, float* __restrict__ amap)
{
    __shared__ float tile[CC][10][10];   // 25.6 KB
    const int w0 = blockIdx.x*8, h0 = blockIdx.y*8, b = blockIdx.z;
    const int t = threadIdx.x;
    const float* xb = x + (size_t)b*CC*HWs;
    for(int idx=t; idx<CC*100; idx+=64){
        int ch = idx/100; int rem = idx%100; int r = rem/10, c2 = rem%10;
        int gh = h0-1+r, gw = w0-1+c2;
        float val = 0.f;
        if(gh>=0 && gh<HH && gw>=0 && gw<WW) val = xb[ch*HWs + gh*WW + gw];
        tile[ch][r][c2] = val;
    }
    __syncthreads();
    const int r = t>>3, c = t&7;
    float acc[32];
    #pragma unroll
    for(int o=0;o<32;o++) acc[o] = bab1[o];
    float edge = 0.f;
    for(int ic=0; ic<CC; ic++){
        float v0=tile[ic][r  ][c], v1=tile[ic][r  ][c+1], v2=tile[ic][r  ][c+2];
        float v3=tile[ic][r+1][c], v4=tile[ic][r+1][c+1], v5=tile[ic][r+1][c+2];
        float v6=tile[ic][r+2][c], v7=tile[ic][r+2][c+1], v8=tile[ic][r+2][c+2];
        // group-conv sobel: channels 0..31 contribute |gx|, 32..63 |gy| (each x2, /64 -> /32)
        if(ic<32) edge += fabsf((v2-v0) + 2.f*(v5-v3) + (v8-v6));
        else      edge += fabsf((v6-v0) + 2.f*(v7-v1) + (v8-v2));
        const float* wp = ws + BAWt + ic*288;   // [j][o32], contiguous -> s_load batches
        #pragma unroll
        for(int o=0;o<32;o++){
            acc[o] += wp[o]*v0 + wp[32+o]*v1 + wp[64+o]*v2
                    + wp[96+o]*v3 + wp[128+o]*v4 + wp[160+o]*v5
                    + wp[192+o]*v6 + wp[224+o]*v7 + wp[256+o]*v8;
        }
    }
    float av = bab2[0];
    #pragma unroll
    for(int o=0;o<32;o++) av += fmaxf(acc[o],0.f)*baw2[o];
    float z = av + edge*(1.f/32.f);
    float sig = 1.f/(1.f+__expf(-z));
    amap[b*HWs + (h0+r)*WW + (w0+c)] = 1.f + sig;
}

// ============ K2: fused xa + dyn1d: fus_o = (A*sum_x) * (A*(W@x)_o + b_o) ============
__global__ __launch_bounds__(256)
void k_xafuse(const float* __restrict__ x, const float* __restrict__ ws,
              bf16* __restrict__ fus)
{
    int p = blockIdx.x*256 + threadIdx.x;
    int b = p / HWs, pp = p % HWs;
    float A = ws[AMAP + p];
    const float* xb = x + (size_t)b*CC*HWs + pp;
    float dot[64];
    #pragma unroll
    for(int o=0;o<64;o++) dot[o] = 0.f;
    float sx = 0.f;
    for(int c=0;c<CC;c++){
        float v = xb[c*HWs];
        sx += v;
        const float* wr = ws + W1X1 + c*64;   // contiguous 64 -> s_load_dwordx16 x4
        #pragma unroll
        for(int o=0;o<64;o++) dot[o] = fmaf(wr[o], v, dot[o]);
    }
    float s = sx * A;
    bf16* fb = fus + (size_t)b*CC*HWs + pp;
    #pragma unroll
    for(int o=0;o<64;o++){
        float f = s * (A*dot[o] + ws[B1X1+o]);
        fb[o*HWs] = f2bf(f);
    }
}

// ============ K3: sf 3x3 conv 64->64 (BN folded) + ReLU ============
#define TIC 16
__global__ __launch_bounds__(256)
void k_sfconv(const bf16* __restrict__ fus, const float* __restrict__ ws,
              bf16* __restrict__ y1)
{
    __shared__ float tile[TIC][18][18];  // 20.7 KB
    int bw = blockIdx.x % 10;
    int bh = (blockIdx.x/10) % 10;
    int b  = (blockIdx.x/100) % 4;
    int og = blockIdx.x/400;             // 0..3 (16 output channels each)
    int t = threadIdx.x;
    int w0 = bw*16, h0 = bh*16;
    int r = t>>4, c = t&15;
    float acc[16];
    #pragma unroll
    for(int o=0;o<16;o++) acc[o] = 0.f;
    const bf16* fb = fus + (size_t)b*CC*HWs;
    for(int icb=0; icb<CC; icb+=TIC){
        __syncthreads();
        for(int idx=t; idx<TIC*324; idx+=256){
            int ch = idx/324; int rem = idx%324; int rr = rem/18, cc2 = rem%18;
            int gh = h0-1+rr, gw = w0-1+cc2;
            float val = 0.f;
            if(gh>=0&&gh<HH&&gw>=0&&gw<WW) val = bf2f(fb[(icb+ch)*HWs + gh*WW + gw]);
            tile[ch][rr][cc2] = val;
        }
        __syncthreads();
        for(int ic=0; ic<TIC; ic++){
            float v0=tile[ic][r  ][c], v1=tile[ic][r  ][c+1], v2=tile[ic][r  ][c+2];
            float v3=tile[ic][r+1][c], v4=tile[ic][r+1][c+1], v5=tile[ic][r+1][c+2];
            float v6=tile[ic][r+2][c], v7=tile[ic][r+2][c+1], v8=tile[ic][r+2][c+2];
            const float* wp = ws + SFWt + (og*64 + icb+ic)*144;  // [j][o16]
            #pragma unroll
            for(int o=0;o<16;o++){
                acc[o] += wp[o]*v0 + wp[16+o]*v1 + wp[32+o]*v2
                        + wp[48+o]*v3 + wp[64+o]*v4 + wp[80+o]*v5
                        + wp[96+o]*v6 + wp[112+o]*v7 + wp[128+o]*v8;
            }
        }
    }
    bf16* yb = y1 + (size_t)(b*CC + og*16)*HWs + (h0+r)*WW + (w0+c);
    #pragma unroll
    for(int o=0;o<16;o++){
        float yv = fmaxf(acc[o] + ws[SFBo + og*16 + o], 0.f);
        yb[o*HWs] = f2bf(yv);
    }
}

// ============ K4: fc 1x1 + bias + residual -> out (fp32) ============
__global__ __launch_bounds__(256)
void k_fc(const bf16* __restrict__ y1, const float* __restrict__ x,
          const float* __restrict__ ws, const float* __restrict__ fcb,
          float* __restrict__ out)
{
    int p = blockIdx.x*256 + threadIdx.x;
    int b = p / HWs, pp = p % HWs;
    const bf16* yb = y1 + (size_t)b*CC*HWs + pp;
    float acc[64];
    #pragma unroll
    for(int o=0;o<64;o++) acc[o] = 0.f;
    for(int c=0;c<CC;c++){
        float v = bf2f(yb[c*HWs]);
        const float* wr = ws + FCWt + c*64;
        #pragma unroll
        for(int o=0;o<64;o++) acc[o] = fmaf(wr[o], v, acc[o]);
    }
    const float* xb = x + (size_t)b*CC*HWs + pp;
    float* ob = out + (size_t)b*CC*HWs + pp;
    #pragma unroll
    for(int o=0;o<64;o++) ob[o*HWs] = acc[o] + fcb[o] + xb[o*HWs];
}

extern "C" void kernel_launch(void* const* d_in, const int* in_sizes, int n_in,
                              void* d_out, int out_size, void* d_ws, size_t ws_size,
                              hipStream_t stream)
{
    const float* x     = (const float*)d_in[0];
    const float* ba_w1 = (const float*)d_in[1];
    const float* ba_b1 = (const float*)d_in[2];
    const float* ba_w2 = (const float*)d_in[3];
    const float* ba_b2 = (const float*)d_in[4];
    // d_in[5..12] = offset branch: dead code in the reference (never used in output)
    const float* rk5_w = (const float*)d_in[13];
    const float* rk5_b = (const float*)d_in[14];
    const float* rk7_w = (const float*)d_in[15];
    const float* rk7_b = (const float*)d_in[16];
    const float* lk5_w = (const float*)d_in[17];
    const float* lk5_b = (const float*)d_in[18];
    const float* lk7_w = (const float*)d_in[19];
    const float* lk7_b = (const float*)d_in[20];
    const float* sf_w  = (const float*)d_in[21];
    const float* sf_b  = (const float*)d_in[22];
    const float* bng   = (const float*)d_in[23];
    const float* bnb   = (const float*)d_in[24];
    const float* bnm   = (const float*)d_in[25];
    const float* bnv   = (const float*)d_in[26];
    const float* fc_w  = (const float*)d_in[27];
    const float* fc_b  = (const float*)d_in[28];

    float* wsf = (float*)d_ws;
    bf16* FUS = (bf16*)((char*)d_ws + (size_t)WS_FLOATS*4);
    bf16* Y1  = FUS + (size_t)BB*CC*HWs;
    float* out = (float*)d_out;

    k_prep<<<64, 256, 0, stream>>>(rk5_w,rk5_b,rk7_w,rk7_b,lk5_w,lk5_b,lk7_w,lk7_b,
                                   sf_w,sf_b,bng,bnb,bnm,bnv, ba_w1, fc_w, wsf);
    k_attn<<<dim3(20,20,4), 64, 0, stream>>>(x, ba_b1, ba_w2, ba_b2, wsf, wsf + AMAP);
    k_xafuse<<<NPIX/256, 256, 0, stream>>>(x, wsf, FUS);
    k_sfconv<<<1600, 256, 0, stream>>>(FUS, wsf, Y1);
    k_fc<<<NPIX/256, 256, 0, stream>>>(Y1, x, wsf, fc_b, out);
}

// Round 3
// 403.818 us; speedup vs baseline: 1.4482x; 1.4482x over previous
//
#include <hip/hip_runtime.h>
#include <hip/hip_bf16.h>
#include <math.h>

#define BB 4
#define CC 64
#define HH 160
#define WW 160
#define HWs (HH*WW)        // 25600
#define NPIX (BB*HWs)      // 102400

using bf16 = __hip_bfloat16;
__device__ __forceinline__ float bf2f(bf16 v){ return __bfloat162float(v); }
__device__ __forceinline__ bf16 f2bf(float v){ return __float2bfloat16(v); }

// ---- workspace layout (float offsets) ----
constexpr int ZA0  = 0;                    // NPIX  : attn partial (oc 0..15) + bias + edge
constexpr int ZA1  = ZA0 + NPIX;           // NPIX  : attn partial (oc 16..31)
constexpr int W1X1 = ZA1 + NPIX;           // 4096  : fused dyn1d 1x1 weights, layout [c][o]
constexpr int B1X1 = W1X1 + 4096;          // 64    : summed dyn1d biases
constexpr int SFWt = B1X1 + 64;            // 36864 : BN-scaled sf weights, [og][ic][j][o16]
constexpr int SFBo = SFWt + 36864;         // 64    : BN-folded sf bias
constexpr int BAWt = SFBo + 64;            // 18432 : ba_w1 transposed [ic][og][j][o16]
constexpr int FCWt = BAWt + 18432;         // 4096  : fc_w transposed [c][o]
constexpr int WS_FLOATS = FCWt + 4096;
// bf16 region after that: FUS, Y1 each BB*CC*HWs = 6,553,600 elems (13.1 MB each)

// ================= K0: weight prep (folds + transposes), all fp32 =================
__global__ void k_prep(const float* __restrict__ rk5w, const float* __restrict__ rk5b,
                       const float* __restrict__ rk7w, const float* __restrict__ rk7b,
                       const float* __restrict__ lk5w, const float* __restrict__ lk5b,
                       const float* __restrict__ lk7w, const float* __restrict__ lk7b,
                       const float* __restrict__ sfw,  const float* __restrict__ sfb,
                       const float* __restrict__ bng,  const float* __restrict__ bnb,
                       const float* __restrict__ bnm,  const float* __restrict__ bnv,
                       const float* __restrict__ baw1, const float* __restrict__ fcw,
                       float* __restrict__ ws)
{
    int tid = blockIdx.x*blockDim.x + threadIdx.x;
    int nt  = gridDim.x*blockDim.x;
    // fused dyn1d 1x1 weights: W[c][o] = sum_k kw[(oo*K+k)*64 + c]
    for(int idx=tid; idx<4096; idx+=nt){
        int c = idx>>6, o = idx&63;
        int grp = o>>4, oo = o&15;
        int K = (grp&1)?7:5;
        const float* w = (grp==0)?rk5w:(grp==1)?rk7w:(grp==2)?lk5w:lk7w;
        float s = 0.f;
        for(int k=0;k<K;k++) s += w[(oo*K+k)*64 + c];
        ws[W1X1 + c*64 + o] = s;
    }
    for(int o=tid;o<64;o+=nt){
        int grp=o>>4, oo=o&15; int K=(grp&1)?7:5;
        const float* bp = (grp==0)?rk5b:(grp==1)?rk7b:(grp==2)?lk5b:lk7b;
        float s=0.f; for(int k=0;k<K;k++) s += bp[oo*K+k];
        ws[B1X1+o]=s;
    }
    // sf conv, BN scale folded into weights, transposed to [og][ic][j][o16]
    for(int idx=tid; idx<36864; idx+=nt){
        int o  = idx & 15;
        int j  = (idx>>4) % 9;
        int ic = (idx/144) & 63;
        int og = idx/(144*64);
        int oc = og*16 + o;
        float sc = bng[oc]*rsqrtf(bnv[oc]+1e-5f);
        ws[SFWt+idx] = sfw[(oc*64 + ic)*9 + j] * sc;
    }
    for(int oc=tid;oc<64;oc+=nt){
        float sc = bng[oc]*rsqrtf(bnv[oc]+1e-5f);
        ws[SFBo+oc] = sfb[oc]*sc + bnb[oc] - bnm[oc]*sc;
    }
    // ba_w1 transposed to [ic][og][j][o16]
    for(int idx=tid; idx<18432; idx+=nt){
        int o  = idx & 15;
        int j  = (idx>>4) % 9;
        int og = (idx/144) & 1;
        int ic = idx/288;
        ws[BAWt+idx] = baw1[((og*16+o)*64 + ic)*9 + j];
    }
    // fc_w transposed to [c][o]
    for(int idx=tid; idx<4096; idx+=nt){
        int o = idx & 63, c = idx>>6;
        ws[FCWt+idx] = fcw[o*64 + c];
    }
}

// ============ K1: fused sobel-edge + attention conv, pre-sigmoid partials ============
// 8x16 pixel tile, 128 threads, 16-ch LDS staging, oc split 16/16 across blockIdx.z&1.
__global__ __launch_bounds__(128)
void k_attn(const float* __restrict__ x, const float* __restrict__ bab1,
            const float* __restrict__ baw2, const float* __restrict__ bab2,
            const float* __restrict__ ws, float* __restrict__ za)
{
    __shared__ float tile[16][10][18];   // 11.52 KB
    const int bw = blockIdx.x, bh = blockIdx.y;
    const int b  = blockIdx.z >> 1, og = blockIdx.z & 1;
    const int t  = threadIdx.x;
    const int w0 = bw*16, h0 = bh*8;
    const int r = t>>4, c = t&15;
    const float* xb = x + (size_t)b*CC*HWs;
    float acc[16];
    #pragma unroll
    for(int o=0;o<16;o++) acc[o] = bab1[og*16+o];
    float edge = 0.f;
    for(int icb=0; icb<CC; icb+=16){
        __syncthreads();
        for(int idx=t; idx<16*180; idx+=128){
            int ch = idx/180; int rem = idx%180; int rr = rem/18, cc2 = rem%18;
            int gh = h0-1+rr, gw = w0-1+cc2;
            float v = 0.f;
            if(gh>=0 && gh<HH && gw>=0 && gw<WW) v = xb[(icb+ch)*HWs + gh*WW + gw];
            tile[ch][rr][cc2] = v;
        }
        __syncthreads();
        for(int ic=0; ic<16; ic++){
            float v0=tile[ic][r  ][c], v1=tile[ic][r  ][c+1], v2=tile[ic][r  ][c+2];
            float v3=tile[ic][r+1][c], v4=tile[ic][r+1][c+1], v5=tile[ic][r+1][c+2];
            float v6=tile[ic][r+2][c], v7=tile[ic][r+2][c+1], v8=tile[ic][r+2][c+2];
            if(og==0){
                // group-conv sobel: ch 0..31 -> |gx|, 32..63 -> |gy| (x2 each, mean/64)
                if(icb<32) edge += fabsf((v2-v0) + 2.f*(v5-v3) + (v8-v6));
                else       edge += fabsf((v6-v0) + 2.f*(v7-v1) + (v8-v2));
            }
            const float* wp = ws + BAWt + ((size_t)(icb+ic)*2 + og)*144;  // [j][o16]
            #pragma unroll
            for(int o=0;o<16;o++){
                acc[o] += wp[o]*v0 + wp[16+o]*v1 + wp[32+o]*v2
                        + wp[48+o]*v3 + wp[64+o]*v4 + wp[80+o]*v5
                        + wp[96+o]*v6 + wp[112+o]*v7 + wp[128+o]*v8;
            }
        }
    }
    float partial = 0.f;
    #pragma unroll
    for(int o=0;o<16;o++) partial += fmaxf(acc[o],0.f)*baw2[og*16+o];
    if(og==0) partial += bab2[0] + edge*(1.f/32.f);
    za[(size_t)og*NPIX + b*HWs + (h0+r)*WW + (w0+c)] = partial;
}

// ======= K2: fused sigmoid + xa + dyn1d: fus_o = (A*sum_x) * (A*(W@x)_o + b_o) =======
// oc split 32/32 across blockIdx.y.
__global__ __launch_bounds__(256)
void k_xafuse(const float* __restrict__ x, const float* __restrict__ ws,
              bf16* __restrict__ fus)
{
    int p = blockIdx.x*256 + threadIdx.x;
    int half = blockIdx.y;
    int b = p / HWs, pp = p % HWs;
    float z = ws[ZA0 + p] + ws[ZA1 + p];
    float A = 1.f + 1.f/(1.f+__expf(-z));
    const float* xb = x + (size_t)b*CC*HWs + pp;
    float dot[32];
    #pragma unroll
    for(int o=0;o<32;o++) dot[o] = 0.f;
    float sx = 0.f;
    for(int c=0;c<CC;c++){
        float v = xb[c*HWs];
        sx += v;
        const float* wr = ws + W1X1 + c*64 + half*32;
        #pragma unroll
        for(int o=0;o<32;o++) dot[o] = fmaf(wr[o], v, dot[o]);
    }
    float s = sx * A;
    bf16* fb = fus + (size_t)(b*CC + half*32)*HWs + pp;
    #pragma unroll
    for(int o=0;o<32;o++){
        float f = s * (A*dot[o] + ws[B1X1 + half*32 + o]);
        fb[o*HWs] = f2bf(f);
    }
}

// ============ K3: sf 3x3 conv 64->64 (BN folded) + ReLU ============
#define TIC 16
__global__ __launch_bounds__(256)
void k_sfconv(const bf16* __restrict__ fus, const float* __restrict__ ws,
              bf16* __restrict__ y1)
{
    __shared__ float tile[TIC][18][18];  // 20.7 KB
    int bw = blockIdx.x % 10;
    int bh = (blockIdx.x/10) % 10;
    int b  = (blockIdx.x/100) % 4;
    int og = blockIdx.x/400;             // 0..3 (16 output channels each)
    int t = threadIdx.x;
    int w0 = bw*16, h0 = bh*16;
    int r = t>>4, c = t&15;
    float acc[16];
    #pragma unroll
    for(int o=0;o<16;o++) acc[o] = 0.f;
    const bf16* fb = fus + (size_t)b*CC*HWs;
    for(int icb=0; icb<CC; icb+=TIC){
        __syncthreads();
        for(int idx=t; idx<TIC*324; idx+=256){
            int ch = idx/324; int rem = idx%324; int rr = rem/18, cc2 = rem%18;
            int gh = h0-1+rr, gw = w0-1+cc2;
            float val = 0.f;
            if(gh>=0&&gh<HH&&gw>=0&&gw<WW) val = bf2f(fb[(icb+ch)*HWs + gh*WW + gw]);
            tile[ch][rr][cc2] = val;
        }
        __syncthreads();
        for(int ic=0; ic<TIC; ic++){
            float v0=tile[ic][r  ][c], v1=tile[ic][r  ][c+1], v2=tile[ic][r  ][c+2];
            float v3=tile[ic][r+1][c], v4=tile[ic][r+1][c+1], v5=tile[ic][r+1][c+2];
            float v6=tile[ic][r+2][c], v7=tile[ic][r+2][c+1], v8=tile[ic][r+2][c+2];
            const float* wp = ws + SFWt + (og*64 + icb+ic)*144;  // [j][o16]
            #pragma unroll
            for(int o=0;o<16;o++){
                acc[o] += wp[o]*v0 + wp[16+o]*v1 + wp[32+o]*v2
                        + wp[48+o]*v3 + wp[64+o]*v4 + wp[80+o]*v5
                        + wp[96+o]*v6 + wp[112+o]*v7 + wp[128+o]*v8;
            }
        }
    }
    bf16* yb = y1 + (size_t)(b*CC + og*16)*HWs + (h0+r)*WW + (w0+c);
    #pragma unroll
    for(int o=0;o<16;o++){
        float yv = fmaxf(acc[o] + ws[SFBo + og*16 + o], 0.f);
        yb[o*HWs] = f2bf(yv);
    }
}

// ============ K4: fc 1x1 + bias + residual -> out (fp32), oc split 32/32 ============
__global__ __launch_bounds__(256)
void k_fc(const bf16* __restrict__ y1, const float* __restrict__ x,
          const float* __restrict__ ws, const float* __restrict__ fcb,
          float* __restrict__ out)
{
    int p = blockIdx.x*256 + threadIdx.x;
    int half = blockIdx.y;
    int b = p / HWs, pp = p % HWs;
    const bf16* yb = y1 + (size_t)b*CC*HWs + pp;
    float acc[32];
    #pragma unroll
    for(int o=0;o<32;o++) acc[o] = 0.f;
    for(int c=0;c<CC;c++){
        float v = bf2f(yb[c*HWs]);
        const float* wr = ws + FCWt + c*64 + half*32;
        #pragma unroll
        for(int o=0;o<32;o++) acc[o] = fmaf(wr[o], v, acc[o]);
    }
    const float* xb = x + (size_t)(b*CC + half*32)*HWs + pp;
    float* ob = out + (size_t)(b*CC + half*32)*HWs + pp;
    #pragma unroll
    for(int o=0;o<32;o++) ob[o*HWs] = acc[o] + fcb[half*32+o] + xb[o*HWs];
}

extern "C" void kernel_launch(void* const* d_in, const int* in_sizes, int n_in,
                              void* d_out, int out_size, void* d_ws, size_t ws_size,
                              hipStream_t stream)
{
    const float* x     = (const float*)d_in[0];
    const float* ba_w1 = (const float*)d_in[1];
    const float* ba_b1 = (const float*)d_in[2];
    const float* ba_w2 = (const float*)d_in[3];
    const float* ba_b2 = (const float*)d_in[4];
    // d_in[5..12] = offset branch: dead code in the reference (never reaches the output)
    const float* rk5_w = (const float*)d_in[13];
    const float* rk5_b = (const float*)d_in[14];
    const float* rk7_w = (const float*)d_in[15];
    const float* rk7_b = (const float*)d_in[16];
    const float* lk5_w = (const float*)d_in[17];
    const float* lk5_b = (const float*)d_in[18];
    const float* lk7_w = (const float*)d_in[19];
    const float* lk7_b = (const float*)d_in[20];
    const float* sf_w  = (const float*)d_in[21];
    const float* sf_b  = (const float*)d_in[22];
    const float* bng   = (const float*)d_in[23];
    const float* bnb   = (const float*)d_in[24];
    const float* bnm   = (const float*)d_in[25];
    const float* bnv   = (const float*)d_in[26];
    const float* fc_w  = (const float*)d_in[27];
    const float* fc_b  = (const float*)d_in[28];

    float* wsf = (float*)d_ws;
    bf16* FUS = (bf16*)((char*)d_ws + (size_t)WS_FLOATS*4);
    bf16* Y1  = FUS + (size_t)BB*CC*HWs;
    float* out = (float*)d_out;

    k_prep<<<64, 256, 0, stream>>>(rk5_w,rk5_b,rk7_w,rk7_b,lk5_w,lk5_b,lk7_w,lk7_b,
                                   sf_w,sf_b,bng,bnb,bnm,bnv, ba_w1, fc_w, wsf);
    k_attn<<<dim3(10,20,8), 128, 0, stream>>>(x, ba_b1, ba_w2, ba_b2, wsf, wsf);
    k_xafuse<<<dim3(NPIX/256,2), 256, 0, stream>>>(x, wsf, FUS);
    k_sfconv<<<1600, 256, 0, stream>>>(FUS, wsf, Y1);
    k_fc<<<dim3(NPIX/256,2), 256, 0, stream>>>(Y1, x, wsf, fc_b, out);
}

// Round 4
// 298.253 us; speedup vs baseline: 1.9607x; 1.3539x over previous
//
#include <hip/hip_runtime.h>
#include <hip/hip_bf16.h>
#include <math.h>

#define BB 4
#define CC 64
#define HH 160
#define WW 160
#define HWs (HH*WW)        // 25600
#define NPIX (BB*HWs)      // 102400

using bf16 = __hip_bfloat16;
typedef __attribute__((ext_vector_type(8))) short short8v;   // 8 x bf16 bits (4 VGPRs)
typedef __attribute__((ext_vector_type(4))) float float4v;   // MFMA accumulator

__device__ __forceinline__ unsigned short f2bfu(float f){
    union { bf16 h; unsigned short u; } cv; cv.h = __float2bfloat16(f); return cv.u;
}
__device__ __forceinline__ float bfu2f(unsigned short u){
    union { float f; unsigned int i; } cv; cv.i = ((unsigned int)u)<<16; return cv.f;
}

// ---- workspace layout (float offsets) ----
constexpr int ZA0  = 0;                    // NPIX  : attn partial (oc 0..15) + bias + edge
constexpr int ZA1  = ZA0 + NPIX;           // NPIX  : attn partial (oc 16..31)
constexpr int W1X1 = ZA1 + NPIX;           // 4096  : fused dyn1d 1x1 weights [c][o]
constexpr int B1X1 = W1X1 + 4096;          // 64
constexpr int SFBo = B1X1 + 64;            // 64    : BN-folded sf bias
constexpr int BAWt = SFBo + 64;            // 18432 : ba_w1 transposed [ic][og][j][o16]
constexpr int FCWt = BAWt + 18432;         // 4096  : fc_w transposed [c][o]
constexpr int SFWf = FCWt + 4096;          // 18432 floats = 36864 bf16: sf weights in
                                           //   MFMA A-frag order [og][tap][kc][lane][j]
constexpr int WS_FLOATS = SFWf + 18432;    // 249984 floats = 999,936 B (16B-aligned)
// bf16 NHWC region after: FUS [b][p][c], Y1 [b][p][c], each 6,553,600 elems

// ================= K0: weight prep (folds + transposes + MFMA pack) =================
__global__ void k_prep(const float* __restrict__ rk5w, const float* __restrict__ rk5b,
                       const float* __restrict__ rk7w, const float* __restrict__ rk7b,
                       const float* __restrict__ lk5w, const float* __restrict__ lk5b,
                       const float* __restrict__ lk7w, const float* __restrict__ lk7b,
                       const float* __restrict__ sfw,  const float* __restrict__ sfb,
                       const float* __restrict__ bng,  const float* __restrict__ bnb,
                       const float* __restrict__ bnm,  const float* __restrict__ bnv,
                       const float* __restrict__ baw1, const float* __restrict__ fcw,
                       float* __restrict__ ws)
{
    int tid = blockIdx.x*blockDim.x + threadIdx.x;
    int nt  = gridDim.x*blockDim.x;
    // fused dyn1d 1x1 weights: W[c][o] = sum_k kw[(oo*K+k)*64 + c]
    for(int idx=tid; idx<4096; idx+=nt){
        int c = idx>>6, o = idx&63;
        int grp = o>>4, oo = o&15;
        int K = (grp&1)?7:5;
        const float* w = (grp==0)?rk5w:(grp==1)?rk7w:(grp==2)?lk5w:lk7w;
        float s = 0.f;
        for(int k=0;k<K;k++) s += w[(oo*K+k)*64 + c];
        ws[W1X1 + c*64 + o] = s;
    }
    for(int o=tid;o<64;o+=nt){
        int grp=o>>4, oo=o&15; int K=(grp&1)?7:5;
        const float* bp = (grp==0)?rk5b:(grp==1)?rk7b:(grp==2)?lk5b:lk7b;
        float s=0.f; for(int k=0;k<K;k++) s += bp[oo*K+k];
        ws[B1X1+o]=s;
    }
    // sf weights, BN-scaled, packed in MFMA A-fragment order:
    // linear = og*9216 + tap*1024 + kc*512 + lane*8 + j
    // oc = og*16 + (lane&15); ic = kc*32 + (lane>>4)*8 + j
    unsigned short* sfwf = (unsigned short*)(ws + SFWf);
    for(int idx=tid; idx<36864; idx+=nt){
        int og = idx/9216;  int rem = idx - og*9216;
        int tp = rem/1024;  int rem2 = rem - tp*1024;
        int kc = rem2>>9;   int rem3 = rem2 & 511;
        int lane = rem3>>3; int j = rem3&7;
        int oc = og*16 + (lane&15);
        int ic = kc*32 + (lane>>4)*8 + j;
        float sc = bng[oc]*rsqrtf(bnv[oc]+1e-5f);
        sfwf[idx] = f2bfu(sfw[(oc*64+ic)*9 + tp] * sc);
    }
    for(int oc=tid;oc<64;oc+=nt){
        float sc = bng[oc]*rsqrtf(bnv[oc]+1e-5f);
        ws[SFBo+oc] = sfb[oc]*sc + bnb[oc] - bnm[oc]*sc;
    }
    // ba_w1 transposed to [ic][og][j][o16]
    for(int idx=tid; idx<18432; idx+=nt){
        int o  = idx & 15;
        int j  = (idx>>4) % 9;
        int og = (idx/144) & 1;
        int ic = idx/288;
        ws[BAWt+idx] = baw1[((og*16+o)*64 + ic)*9 + j];
    }
    // fc_w transposed to [c][o]
    for(int idx=tid; idx<4096; idx+=nt){
        int o = idx & 63, c = idx>>6;
        ws[FCWt+idx] = fcw[o*64 + c];
    }
}

// ============ K1: fused sobel-edge + attention conv, pre-sigmoid partials ============
__global__ __launch_bounds__(128)
void k_attn(const float* __restrict__ x, const float* __restrict__ bab1,
            const float* __restrict__ baw2, const float* __restrict__ bab2,
            const float* __restrict__ ws, float* __restrict__ za)
{
    __shared__ float tile[16][10][18];   // 11.52 KB
    const int bw = blockIdx.x, bh = blockIdx.y;
    const int b  = blockIdx.z >> 1, og = blockIdx.z & 1;
    const int t  = threadIdx.x;
    const int w0 = bw*16, h0 = bh*8;
    const int r = t>>4, c = t&15;
    const float* xb = x + (size_t)b*CC*HWs;
    float acc[16];
    #pragma unroll
    for(int o=0;o<16;o++) acc[o] = bab1[og*16+o];
    float edge = 0.f;
    for(int icb=0; icb<CC; icb+=16){
        __syncthreads();
        for(int idx=t; idx<16*180; idx+=128){
            int ch = idx/180; int rem = idx%180; int rr = rem/18, cc2 = rem%18;
            int gh = h0-1+rr, gw = w0-1+cc2;
            float v = 0.f;
            if(gh>=0 && gh<HH && gw>=0 && gw<WW) v = xb[(icb+ch)*HWs + gh*WW + gw];
            tile[ch][rr][cc2] = v;
        }
        __syncthreads();
        for(int ic=0; ic<16; ic++){
            float v0=tile[ic][r  ][c], v1=tile[ic][r  ][c+1], v2=tile[ic][r  ][c+2];
            float v3=tile[ic][r+1][c], v4=tile[ic][r+1][c+1], v5=tile[ic][r+1][c+2];
            float v6=tile[ic][r+2][c], v7=tile[ic][r+2][c+1], v8=tile[ic][r+2][c+2];
            if(og==0){
                if(icb<32) edge += fabsf((v2-v0) + 2.f*(v5-v3) + (v8-v6));
                else       edge += fabsf((v6-v0) + 2.f*(v7-v1) + (v8-v2));
            }
            const float* wp = ws + BAWt + ((size_t)(icb+ic)*2 + og)*144;
            #pragma unroll
            for(int o=0;o<16;o++){
                acc[o] += wp[o]*v0 + wp[16+o]*v1 + wp[32+o]*v2
                        + wp[48+o]*v3 + wp[64+o]*v4 + wp[80+o]*v5
                        + wp[96+o]*v6 + wp[112+o]*v7 + wp[128+o]*v8;
            }
        }
    }
    float partial = 0.f;
    #pragma unroll
    for(int o=0;o<16;o++) partial += fmaxf(acc[o],0.f)*baw2[og*16+o];
    if(og==0) partial += bab2[0] + edge*(1.f/32.f);
    za[(size_t)og*NPIX + b*HWs + (h0+r)*WW + (w0+c)] = partial;
}

// ======= K2: sigmoid + xa + dyn1d -> FUS in NHWC bf16 =======
__global__ __launch_bounds__(128)
void k_xafuse(const float* __restrict__ x, const float* __restrict__ ws,
              unsigned short* __restrict__ fus)
{
    int p = blockIdx.x*128 + threadIdx.x;
    int b = p / HWs, pp = p % HWs;
    float z = ws[ZA0 + p] + ws[ZA1 + p];
    float A = 1.f + 1.f/(1.f+__expf(-z));
    const float* xb = x + (size_t)b*CC*HWs + pp;
    float dot[64];
    #pragma unroll
    for(int o=0;o<64;o++) dot[o] = 0.f;
    float sx = 0.f;
    for(int c=0;c<CC;c++){
        float v = xb[c*HWs];
        sx += v;
        const float* wr = ws + W1X1 + c*64;
        #pragma unroll
        for(int o=0;o<64;o++) dot[o] = fmaf(wr[o], v, dot[o]);
    }
    float s = sx * A;
    unsigned short* fb = fus + (size_t)p*64;
    #pragma unroll
    for(int ch8=0; ch8<8; ch8++){
        short8v o8;
        #pragma unroll
        for(int j=0;j<8;j++){
            float f = s * (A*dot[ch8*8+j] + ws[B1X1 + ch8*8+j]);
            o8[j] = (short)f2bfu(f);
        }
        *(short8v*)(fb + ch8*8) = o8;
    }
}

// ============ K3: sf 3x3 conv 64->64 via bf16 MFMA implicit GEMM + ReLU ============
// 16x8 pixel tile; LDS halo 18x10 px, NHWC 64ch padded to 72 bf16/px (anti-conflict).
// Each of 4 waves owns 16 oc; A-frags preloaded; B-frags = ds_read_b128.
__global__ __launch_bounds__(256)
void k_sfconv(const unsigned short* __restrict__ fus, const float* __restrict__ ws,
              unsigned short* __restrict__ y1)
{
    __shared__ unsigned short tile[10*18*72];   // 25,920 B
    const int bw = blockIdx.x;   // 0..9  -> w0
    const int bh = blockIdx.y;   // 0..19 -> h0
    const int b  = blockIdx.z;
    const int t  = threadIdx.x;
    const int wave = t>>6, lane = t&63;
    const int quad = lane>>4, n = lane&15;
    const int w0 = bw*16, h0 = bh*8;

    // stage 18x10 halo tile, NHWC, pixel stride 72 bf16
    const unsigned short* fb = fus + (size_t)b*HWs*64;
    for(int idx=t; idx<1440; idx+=256){          // 180 px * 8 chunks
        int sub = idx&7; int pix = idx>>3;
        int row = pix/18, col = pix%18;
        int gh = h0-1+row, gw = w0-1+col;
        short8v v = {0,0,0,0,0,0,0,0};
        if(gh>=0&&gh<HH&&gw>=0&&gw<WW)
            v = *(const short8v*)(fb + ((size_t)(gh*WW+gw))*64 + sub*8);
        *(short8v*)(tile + (row*18+col)*72 + sub*8) = v;
    }
    // preload 18 A-fragments (tap*2+kc) for this wave's 16 oc
    const unsigned short* sfwf = (const unsigned short*)(ws + SFWf);
    short8v afrag[18];
    #pragma unroll
    for(int f=0; f<18; f++)
        afrag[f] = *(const short8v*)(sfwf + (((size_t)wave*18 + f)*64 + lane)*8);
    // bias for this lane's 4 output rows: oc = wave*16 + quad*4 + r
    float bias[4];
    #pragma unroll
    for(int r=0;r<4;r++) bias[r] = ws[SFBo + wave*16 + quad*4 + r];
    __syncthreads();

    // 8 output rows, processed in pairs for MFMA ILP
    #pragma unroll
    for(int srp=0; srp<4; srp++){
        const int r0 = srp*2, r1 = srp*2+1;
        float4v acc0={0,0,0,0}, acc1={0,0,0,0};
        #pragma unroll
        for(int tap=0; tap<9; tap++){
            const int dh = tap/3, dw = tap%3;
            const unsigned short* base0 = tile + ((r0+dh)*18 + dw + n)*72 + quad*8;
            const unsigned short* base1 = tile + ((r1+dh)*18 + dw + n)*72 + quad*8;
            #pragma unroll
            for(int kc=0; kc<2; kc++){
                short8v b0 = *(const short8v*)(base0 + kc*32);
                short8v b1 = *(const short8v*)(base1 + kc*32);
                acc0 = __builtin_amdgcn_mfma_f32_16x16x32_bf16(afrag[tap*2+kc], b0, acc0, 0,0,0);
                acc1 = __builtin_amdgcn_mfma_f32_16x16x32_bf16(afrag[tap*2+kc], b1, acc1, 0,0,0);
            }
        }
        // D layout: col(pixel)=lane&15, row(oc)=quad*4+reg -> 4 consecutive oc per lane
        union { unsigned long long u; unsigned short s[4]; } pk0, pk1;
        #pragma unroll
        for(int r=0;r<4;r++){
            pk0.s[r] = f2bfu(fmaxf(acc0[r] + bias[r], 0.f));
            pk1.s[r] = f2bfu(fmaxf(acc1[r] + bias[r], 0.f));
        }
        unsigned short* yp0 = y1 + ((size_t)b*HWs + (h0+r0)*WW + w0 + n)*64 + wave*16 + quad*4;
        unsigned short* yp1 = y1 + ((size_t)b*HWs + (h0+r1)*WW + w0 + n)*64 + wave*16 + quad*4;
        *(unsigned long long*)yp0 = pk0.u;
        *(unsigned long long*)yp1 = pk1.u;
    }
}

// ============ K4: fc 1x1 + bias + residual -> out (fp32 NCHW) ============
__global__ __launch_bounds__(128)
void k_fc(const unsigned short* __restrict__ y1, const float* __restrict__ x,
          const float* __restrict__ ws, const float* __restrict__ fcb,
          float* __restrict__ out)
{
    int p = blockIdx.x*128 + threadIdx.x;
    int b = p / HWs, pp = p % HWs;
    const unsigned short* yp = y1 + (size_t)p*64;
    float acc[64];
    #pragma unroll
    for(int o=0;o<64;o++) acc[o] = 0.f;
    #pragma unroll
    for(int ch8=0; ch8<8; ch8++){
        short8v y8 = *(const short8v*)(yp + ch8*8);
        #pragma unroll
        for(int j=0;j<8;j++){
            float v = bfu2f((unsigned short)y8[j]);
            const float* wr = ws + FCWt + (ch8*8+j)*64;
            #pragma unroll
            for(int o=0;o<64;o++) acc[o] = fmaf(wr[o], v, acc[o]);
        }
    }
    const float* xb = x + (size_t)b*CC*HWs + pp;
    float* ob = out + (size_t)b*CC*HWs + pp;
    #pragma unroll
    for(int o=0;o<64;o++) ob[o*HWs] = acc[o] + fcb[o] + xb[o*HWs];
}

extern "C" void kernel_launch(void* const* d_in, const int* in_sizes, int n_in,
                              void* d_out, int out_size, void* d_ws, size_t ws_size,
                              hipStream_t stream)
{
    const float* x     = (const float*)d_in[0];
    const float* ba_w1 = (const float*)d_in[1];
    const float* ba_b1 = (const float*)d_in[2];
    const float* ba_w2 = (const float*)d_in[3];
    const float* ba_b2 = (const float*)d_in[4];
    // d_in[5..12] = offset branch: dead code in the reference (never reaches the output)
    const float* rk5_w = (const float*)d_in[13];
    const float* rk5_b = (const float*)d_in[14];
    const float* rk7_w = (const float*)d_in[15];
    const float* rk7_b = (const float*)d_in[16];
    const float* lk5_w = (const float*)d_in[17];
    const float* lk5_b = (const float*)d_in[18];
    const float* lk7_w = (const float*)d_in[19];
    const float* lk7_b = (const float*)d_in[20];
    const float* sf_w  = (const float*)d_in[21];
    const float* sf_b  = (const float*)d_in[22];
    const float* bng   = (const float*)d_in[23];
    const float* bnb   = (const float*)d_in[24];
    const float* bnm   = (const float*)d_in[25];
    const float* bnv   = (const float*)d_in[26];
    const float* fc_w  = (const float*)d_in[27];
    const float* fc_b  = (const float*)d_in[28];

    float* wsf = (float*)d_ws;
    unsigned short* FUS = (unsigned short*)((char*)d_ws + (size_t)WS_FLOATS*4);
    unsigned short* Y1  = FUS + (size_t)BB*HWs*64;
    float* out = (float*)d_out;

    k_prep<<<64, 256, 0, stream>>>(rk5_w,rk5_b,rk7_w,rk7_b,lk5_w,lk5_b,lk7_w,lk7_b,
                                   sf_w,sf_b,bng,bnb,bnm,bnv, ba_w1, fc_w, wsf);
    k_attn<<<dim3(10,20,8), 128, 0, stream>>>(x, ba_b1, ba_w2, ba_b2, wsf, wsf);
    k_xafuse<<<NPIX/128, 128, 0, stream>>>(x, wsf, FUS);
    k_sfconv<<<dim3(10,20,4), 256, 0, stream>>>(FUS, wsf, Y1);
    k_fc<<<NPIX/128, 128, 0, stream>>>(Y1, x, wsf, fc_b, out);
}

// Round 5
// 230.963 us; speedup vs baseline: 2.5320x; 1.2913x over previous
//
#include <hip/hip_runtime.h>
#include <hip/hip_bf16.h>
#include <math.h>

#define BB 4
#define CC 64
#define HH 160
#define WW 160
#define HWs (HH*WW)        // 25600
#define NPIX (BB*HWs)      // 102400

using bf16 = __hip_bfloat16;
typedef __attribute__((ext_vector_type(8))) short short8v;   // 8 x bf16 bits (4 VGPRs)
typedef __attribute__((ext_vector_type(4))) float float4v;   // MFMA accumulator

__device__ __forceinline__ unsigned short f2bfu(float f){
    union { bf16 h; unsigned short u; } cv; cv.h = __float2bfloat16(f); return cv.u;
}
__device__ __forceinline__ float bfu2f(unsigned short u){
    union { float f; unsigned int i; } cv; cv.i = ((unsigned int)u)<<16; return cv.f;
}

// ---- workspace layout (float offsets) ----
constexpr int ZA0  = 0;                    // NPIX  : full pre-sigmoid attn score z
constexpr int W1X1 = ZA0 + NPIX;           // 4096  : fused dyn1d 1x1 weights [c][o]
constexpr int B1X1 = W1X1 + 4096;          // 64
constexpr int SFBo = B1X1 + 64;            // 64    : BN-folded sf bias
constexpr int FCWt = SFBo + 64;            // 4096  : fc_w transposed [c][o]
constexpr int SFWf = FCWt + 4096;          // 18432 floats = 36864 bf16: sf weights A-frag
constexpr int BAWf = SFWf + 18432;         // 9216 floats = 18432 bf16: ba_w1 A-frag
                                           //   [og][tap*2+kc][lane][j]
constexpr int WS_FLOATS = BAWf + 9216;     // 138368 floats = 553,472 B (16B aligned)
// bf16 NHWC region after: FUS [p][c], then Y1 [p][c] (XB aliases Y1 — disjoint lifetime)

// ================= K0: weight prep (folds + transposes + MFMA packs) =================
__global__ void k_prep(const float* __restrict__ rk5w, const float* __restrict__ rk5b,
                       const float* __restrict__ rk7w, const float* __restrict__ rk7b,
                       const float* __restrict__ lk5w, const float* __restrict__ lk5b,
                       const float* __restrict__ lk7w, const float* __restrict__ lk7b,
                       const float* __restrict__ sfw,  const float* __restrict__ sfb,
                       const float* __restrict__ bng,  const float* __restrict__ bnb,
                       const float* __restrict__ bnm,  const float* __restrict__ bnv,
                       const float* __restrict__ baw1, const float* __restrict__ fcw,
                       float* __restrict__ ws)
{
    int tid = blockIdx.x*blockDim.x + threadIdx.x;
    int nt  = gridDim.x*blockDim.x;
    // fused dyn1d 1x1 weights: W[c][o] = sum_k kw[(oo*K+k)*64 + c]
    for(int idx=tid; idx<4096; idx+=nt){
        int c = idx>>6, o = idx&63;
        int grp = o>>4, oo = o&15;
        int K = (grp&1)?7:5;
        const float* w = (grp==0)?rk5w:(grp==1)?rk7w:(grp==2)?lk5w:lk7w;
        float s = 0.f;
        for(int k=0;k<K;k++) s += w[(oo*K+k)*64 + c];
        ws[W1X1 + c*64 + o] = s;
    }
    for(int o=tid;o<64;o+=nt){
        int grp=o>>4, oo=o&15; int K=(grp&1)?7:5;
        const float* bp = (grp==0)?rk5b:(grp==1)?rk7b:(grp==2)?lk5b:lk7b;
        float s=0.f; for(int k=0;k<K;k++) s += bp[oo*K+k];
        ws[B1X1+o]=s;
    }
    // sf weights, BN-scaled, packed in MFMA A-fragment order:
    // idx = og*9216 + tap*1024 + kc*512 + lane*8 + j
    // oc = og*16 + (lane&15); ic = kc*32 + (lane>>4)*8 + j
    unsigned short* sfwf = (unsigned short*)(ws + SFWf);
    for(int idx=tid; idx<36864; idx+=nt){
        int og = idx/9216;  int rem = idx - og*9216;
        int tp = rem/1024;  int rem2 = rem - tp*1024;
        int kc = rem2>>9;   int rem3 = rem2 & 511;
        int lane = rem3>>3; int j = rem3&7;
        int oc = og*16 + (lane&15);
        int ic = kc*32 + (lane>>4)*8 + j;
        float sc = bng[oc]*rsqrtf(bnv[oc]+1e-5f);
        sfwf[idx] = f2bfu(sfw[(oc*64+ic)*9 + tp] * sc);
    }
    for(int oc=tid;oc<64;oc+=nt){
        float sc = bng[oc]*rsqrtf(bnv[oc]+1e-5f);
        ws[SFBo+oc] = sfb[oc]*sc + bnb[oc] - bnm[oc]*sc;
    }
    // ba_w1 packed in MFMA A-frag order: idx = ((og*18 + tap*2+kc)*64 + lane)*8 + j
    unsigned short* bawf = (unsigned short*)(ws + BAWf);
    for(int idx=tid; idx<18432; idx+=nt){
        int og = idx/9216;  int r1 = idx - og*9216;
        int f  = r1/512;    int r2 = r1 & 511;
        int lane = r2>>3;   int j = r2&7;
        int tap = f>>1, kc = f&1;
        int oc = og*16 + (lane&15);
        int ic = kc*32 + (lane>>4)*8 + j;
        bawf[idx] = f2bfu(baw1[(oc*64+ic)*9 + tap]);
    }
    // fc_w transposed to [c][o]
    for(int idx=tid; idx<4096; idx+=nt){
        int o = idx & 63, c = idx>>6;
        ws[FCWt+idx] = fcw[o*64 + c];
    }
}

// ============ K1a: x (fp32 NCHW) -> XB (bf16 NHWC), LDS-tiled transpose ============
__global__ __launch_bounds__(256)
void k_x2nhwc(const float* __restrict__ x, unsigned short* __restrict__ xb)
{
    __shared__ unsigned short ls[64*128];    // [c][px], 16 KB
    const int t = threadIdx.x;
    const int p0 = blockIdx.x*128;
    const int b = p0 / HWs, pp0 = p0 % HWs;
    const float* xbase = x + (size_t)b*CC*HWs + pp0;
    #pragma unroll
    for(int iter=0; iter<32; iter++){
        int idx = iter*256 + t;
        int c = idx>>7, px = idx&127;
        ls[c*128 + px] = f2bfu(xbase[(size_t)c*HWs + px]);
    }
    __syncthreads();
    #pragma unroll
    for(int iter=0; iter<4; iter++){
        int idx = iter*256 + t;
        int sub = idx&7, px = idx>>3;
        short8v v;
        #pragma unroll
        for(int j=0;j<8;j++) v[j] = (short)ls[(sub*8+j)*128 + px];
        *(short8v*)(xb + ((size_t)(p0+px))*64 + sub*8) = v;
    }
}

// ====== K1b: attn conv via bf16 MFMA + sobel edge -> full pre-sigmoid z plane ======
// 16x8 px tile, 256 thr; wave = og*2 + rowgroup. Same LDS geometry as k_sfconv.
__global__ __launch_bounds__(256)
void k_attn(const unsigned short* __restrict__ xb, const float* __restrict__ bab1,
            const float* __restrict__ baw2, const float* __restrict__ bab2,
            const float* __restrict__ ws, float* __restrict__ za)
{
    __shared__ unsigned short tile[10*18*72];  // 25,920 B
    __shared__ float zbuf[2][8][16];
    __shared__ float ebuf[2][128];
    const int bw = blockIdx.x, bh = blockIdx.y, b = blockIdx.z;
    const int t = threadIdx.x;
    const int wave = t>>6, lane = t&63;
    const int quad = lane>>4, n = lane&15;
    const int og = wave&1, rh = wave>>1;
    const int w0 = bw*16, h0 = bh*8;

    const unsigned short* fb = xb + (size_t)b*HWs*64;
    for(int idx=t; idx<1440; idx+=256){
        int sub = idx&7; int pix = idx>>3;
        int row = pix/18, col = pix%18;
        int gh = h0-1+row, gw = w0-1+col;
        short8v v = {0,0,0,0,0,0,0,0};
        if(gh>=0&&gh<HH&&gw>=0&&gw<WW)
            v = *(const short8v*)(fb + ((size_t)(gh*WW+gw))*64 + sub*8);
        *(short8v*)(tile + (row*18+col)*72 + sub*8) = v;
    }
    const unsigned short* bawf = (const unsigned short*)(ws + BAWf);
    short8v afrag[18];
    #pragma unroll
    for(int f=0; f<18; f++)
        afrag[f] = *(const short8v*)(bawf + (((size_t)og*18 + f)*64 + lane)*8);
    float b1[4], w2[4];
    #pragma unroll
    for(int r=0;r<4;r++){
        b1[r] = bab1[og*16 + quad*4 + r];
        w2[r] = baw2[og*16 + quad*4 + r];
    }
    __syncthreads();

    // --- MFMA: 4 rows per wave, in pairs ---
    #pragma unroll
    for(int srp=0; srp<2; srp++){
        const int gr0 = rh*4 + srp*2, gr1 = gr0+1;
        float4v acc0={0,0,0,0}, acc1={0,0,0,0};
        #pragma unroll
        for(int tap=0; tap<9; tap++){
            const int dh = tap/3, dw = tap%3;
            const unsigned short* base0 = tile + ((gr0+dh)*18 + dw + n)*72 + quad*8;
            const unsigned short* base1 = tile + ((gr1+dh)*18 + dw + n)*72 + quad*8;
            #pragma unroll
            for(int kc=0; kc<2; kc++){
                short8v v0 = *(const short8v*)(base0 + kc*32);
                short8v v1 = *(const short8v*)(base1 + kc*32);
                acc0 = __builtin_amdgcn_mfma_f32_16x16x32_bf16(afrag[tap*2+kc], v0, acc0, 0,0,0);
                acc1 = __builtin_amdgcn_mfma_f32_16x16x32_bf16(afrag[tap*2+kc], v1, acc1, 0,0,0);
            }
        }
        // relu + w2-weighted sum over this lane's 4 oc, then quad butterfly
        float c0 = 0.f, c1 = 0.f;
        #pragma unroll
        for(int r=0;r<4;r++){
            c0 += fmaxf(acc0[r] + b1[r], 0.f) * w2[r];
            c1 += fmaxf(acc1[r] + b1[r], 0.f) * w2[r];
        }
        c0 += __shfl_xor(c0, 16); c0 += __shfl_xor(c0, 32);
        c1 += __shfl_xor(c1, 16); c1 += __shfl_xor(c1, 32);
        if(lane < 16){
            zbuf[og][gr0][lane] = c0;
            zbuf[og][gr1][lane] = c1;
        }
    }

    // --- Sobel edge from the same LDS tile ---
    {
        const int half = t>>7, px = t&127;
        const int r = px>>4, c = px&15;
        float e = 0.f;
        #pragma unroll
        for(int s=0; s<4; s++){
            const int sub = half*4 + s;
            if(half==0){   // gx on ch 0..31: cols c, c+2 over rows r..r+2
                short8v a0 = *(const short8v*)(tile + ((r  )*18 + c  )*72 + sub*8);
                short8v a2 = *(const short8v*)(tile + ((r  )*18 + c+2)*72 + sub*8);
                short8v a3 = *(const short8v*)(tile + ((r+1)*18 + c  )*72 + sub*8);
                short8v a5 = *(const short8v*)(tile + ((r+1)*18 + c+2)*72 + sub*8);
                short8v a6 = *(const short8v*)(tile + ((r+2)*18 + c  )*72 + sub*8);
                short8v a8 = *(const short8v*)(tile + ((r+2)*18 + c+2)*72 + sub*8);
                #pragma unroll
                for(int j=0;j<8;j++){
                    float gx = (bfu2f((unsigned short)a2[j]) - bfu2f((unsigned short)a0[j]))
                       + 2.f*(bfu2f((unsigned short)a5[j]) - bfu2f((unsigned short)a3[j]))
                       +      (bfu2f((unsigned short)a8[j]) - bfu2f((unsigned short)a6[j]));
                    e += fabsf(gx);
                }
            } else {       // gy on ch 32..63: rows r, r+2 over cols c..c+2
                short8v b0 = *(const short8v*)(tile + ((r  )*18 + c  )*72 + sub*8);
                short8v b1v= *(const short8v*)(tile + ((r  )*18 + c+1)*72 + sub*8);
                short8v b2 = *(const short8v*)(tile + ((r  )*18 + c+2)*72 + sub*8);
                short8v b6 = *(const short8v*)(tile + ((r+2)*18 + c  )*72 + sub*8);
                short8v b7 = *(const short8v*)(tile + ((r+2)*18 + c+1)*72 + sub*8);
                short8v b8 = *(const short8v*)(tile + ((r+2)*18 + c+2)*72 + sub*8);
                #pragma unroll
                for(int j=0;j<8;j++){
                    float gy = (bfu2f((unsigned short)b6[j]) - bfu2f((unsigned short)b0[j]))
                       + 2.f*(bfu2f((unsigned short)b7[j]) - bfu2f((unsigned short)b1v[j]))
                       +      (bfu2f((unsigned short)b8[j]) - bfu2f((unsigned short)b2[j]));
                    e += fabsf(gy);
                }
            }
        }
        ebuf[half][px] = e;
    }
    __syncthreads();

    if(t < 128){
        const int row = t>>4, col = t&15;
        float z = zbuf[0][row][col] + zbuf[1][row][col] + bab2[0]
                + (ebuf[0][t] + ebuf[1][t]) * (1.f/32.f);
        za[(size_t)b*HWs + (h0+row)*WW + w0 + col] = z;
    }
}

// ======= K2: sigmoid + xa + dyn1d -> FUS in NHWC bf16 =======
__global__ __launch_bounds__(128)
void k_xafuse(const float* __restrict__ x, const float* __restrict__ ws,
              unsigned short* __restrict__ fus)
{
    int p = blockIdx.x*128 + threadIdx.x;
    int b = p / HWs, pp = p % HWs;
    float z = ws[ZA0 + p];
    float A = 1.f + 1.f/(1.f+__expf(-z));
    const float* xb = x + (size_t)b*CC*HWs + pp;
    float dot[64];
    #pragma unroll
    for(int o=0;o<64;o++) dot[o] = 0.f;
    float sx = 0.f;
    for(int c=0;c<CC;c++){
        float v = xb[c*HWs];
        sx += v;
        const float* wr = ws + W1X1 + c*64;
        #pragma unroll
        for(int o=0;o<64;o++) dot[o] = fmaf(wr[o], v, dot[o]);
    }
    float s = sx * A;
    unsigned short* fb = fus + (size_t)p*64;
    #pragma unroll
    for(int ch8=0; ch8<8; ch8++){
        short8v o8;
        #pragma unroll
        for(int j=0;j<8;j++){
            float f = s * (A*dot[ch8*8+j] + ws[B1X1 + ch8*8+j]);
            o8[j] = (short)f2bfu(f);
        }
        *(short8v*)(fb + ch8*8) = o8;
    }
}

// ============ K3: sf 3x3 conv 64->64 via bf16 MFMA implicit GEMM + ReLU ============
__global__ __launch_bounds__(256)
void k_sfconv(const unsigned short* __restrict__ fus, const float* __restrict__ ws,
              unsigned short* __restrict__ y1)
{
    __shared__ unsigned short tile[10*18*72];   // 25,920 B
    const int bw = blockIdx.x, bh = blockIdx.y, b = blockIdx.z;
    const int t  = threadIdx.x;
    const int wave = t>>6, lane = t&63;
    const int quad = lane>>4, n = lane&15;
    const int w0 = bw*16, h0 = bh*8;

    const unsigned short* fb = fus + (size_t)b*HWs*64;
    for(int idx=t; idx<1440; idx+=256){
        int sub = idx&7; int pix = idx>>3;
        int row = pix/18, col = pix%18;
        int gh = h0-1+row, gw = w0-1+col;
        short8v v = {0,0,0,0,0,0,0,0};
        if(gh>=0&&gh<HH&&gw>=0&&gw<WW)
            v = *(const short8v*)(fb + ((size_t)(gh*WW+gw))*64 + sub*8);
        *(short8v*)(tile + (row*18+col)*72 + sub*8) = v;
    }
    const unsigned short* sfwf = (const unsigned short*)(ws + SFWf);
    short8v afrag[18];
    #pragma unroll
    for(int f=0; f<18; f++)
        afrag[f] = *(const short8v*)(sfwf + (((size_t)wave*18 + f)*64 + lane)*8);
    float bias[4];
    #pragma unroll
    for(int r=0;r<4;r++) bias[r] = ws[SFBo + wave*16 + quad*4 + r];
    __syncthreads();

    #pragma unroll
    for(int srp=0; srp<4; srp++){
        const int r0 = srp*2, r1 = srp*2+1;
        float4v acc0={0,0,0,0}, acc1={0,0,0,0};
        #pragma unroll
        for(int tap=0; tap<9; tap++){
            const int dh = tap/3, dw = tap%3;
            const unsigned short* base0 = tile + ((r0+dh)*18 + dw + n)*72 + quad*8;
            const unsigned short* base1 = tile + ((r1+dh)*18 + dw + n)*72 + quad*8;
            #pragma unroll
            for(int kc=0; kc<2; kc++){
                short8v b0 = *(const short8v*)(base0 + kc*32);
                short8v b1 = *(const short8v*)(base1 + kc*32);
                acc0 = __builtin_amdgcn_mfma_f32_16x16x32_bf16(afrag[tap*2+kc], b0, acc0, 0,0,0);
                acc1 = __builtin_amdgcn_mfma_f32_16x16x32_bf16(afrag[tap*2+kc], b1, acc1, 0,0,0);
            }
        }
        union { unsigned long long u; unsigned short s[4]; } pk0, pk1;
        #pragma unroll
        for(int r=0;r<4;r++){
            pk0.s[r] = f2bfu(fmaxf(acc0[r] + bias[r], 0.f));
            pk1.s[r] = f2bfu(fmaxf(acc1[r] + bias[r], 0.f));
        }
        unsigned short* yp0 = y1 + ((size_t)b*HWs + (h0+r0)*WW + w0 + n)*64 + wave*16 + quad*4;
        unsigned short* yp1 = y1 + ((size_t)b*HWs + (h0+r1)*WW + w0 + n)*64 + wave*16 + quad*4;
        *(unsigned long long*)yp0 = pk0.u;
        *(unsigned long long*)yp1 = pk1.u;
    }
}

// ============ K4: fc 1x1 + bias + residual -> out (fp32 NCHW) ============
__global__ __launch_bounds__(128)
void k_fc(const unsigned short* __restrict__ y1, const float* __restrict__ x,
          const float* __restrict__ ws, const float* __restrict__ fcb,
          float* __restrict__ out)
{
    int p = blockIdx.x*128 + threadIdx.x;
    int b = p / HWs, pp = p % HWs;
    const unsigned short* yp = y1 + (size_t)p*64;
    float acc[64];
    #pragma unroll
    for(int o=0;o<64;o++) acc[o] = 0.f;
    #pragma unroll
    for(int ch8=0; ch8<8; ch8++){
        short8v y8 = *(const short8v*)(yp + ch8*8);
        #pragma unroll
        for(int j=0;j<8;j++){
            float v = bfu2f((unsigned short)y8[j]);
            const float* wr = ws + FCWt + (ch8*8+j)*64;
            #pragma unroll
            for(int o=0;o<64;o++) acc[o] = fmaf(wr[o], v, acc[o]);
        }
    }
    const float* xb = x + (size_t)b*CC*HWs + pp;
    float* ob = out + (size_t)b*CC*HWs + pp;
    #pragma unroll
    for(int o=0;o<64;o++) ob[o*HWs] = acc[o] + fcb[o] + xb[o*HWs];
}

extern "C" void kernel_launch(void* const* d_in, const int* in_sizes, int n_in,
                              void* d_out, int out_size, void* d_ws, size_t ws_size,
                              hipStream_t stream)
{
    const float* x     = (const float*)d_in[0];
    const float* ba_w1 = (const float*)d_in[1];
    const float* ba_b1 = (const float*)d_in[2];
    const float* ba_w2 = (const float*)d_in[3];
    const float* ba_b2 = (const float*)d_in[4];
    // d_in[5..12] = offset branch: dead code in the reference (never reaches the output)
    const float* rk5_w = (const float*)d_in[13];
    const float* rk5_b = (const float*)d_in[14];
    const float* rk7_w = (const float*)d_in[15];
    const float* rk7_b = (const float*)d_in[16];
    const float* lk5_w = (const float*)d_in[17];
    const float* lk5_b = (const float*)d_in[18];
    const float* lk7_w = (const float*)d_in[19];
    const float* lk7_b = (const float*)d_in[20];
    const float* sf_w  = (const float*)d_in[21];
    const float* sf_b  = (const float*)d_in[22];
    const float* bng   = (const float*)d_in[23];
    const float* bnb   = (const float*)d_in[24];
    const float* bnm   = (const float*)d_in[25];
    const float* bnv   = (const float*)d_in[26];
    const float* fc_w  = (const float*)d_in[27];
    const float* fc_b  = (const float*)d_in[28];

    float* wsf = (float*)d_ws;
    unsigned short* FUS = (unsigned short*)((char*)d_ws + (size_t)WS_FLOATS*4);
    unsigned short* Y1  = FUS + (size_t)BB*HWs*64;
    unsigned short* XB  = Y1;   // alias: XB dead before k_sfconv writes Y1
    float* out = (float*)d_out;

    k_prep<<<64, 256, 0, stream>>>(rk5_w,rk5_b,rk7_w,rk7_b,lk5_w,lk5_b,lk7_w,lk7_b,
                                   sf_w,sf_b,bng,bnb,bnm,bnv, ba_w1, fc_w, wsf);
    k_x2nhwc<<<NPIX/128, 256, 0, stream>>>(x, XB);
    k_attn<<<dim3(10,20,4), 256, 0, stream>>>(XB, ba_b1, ba_w2, ba_b2, wsf, wsf + ZA0);
    k_xafuse<<<NPIX/128, 128, 0, stream>>>(x, wsf, FUS);
    k_sfconv<<<dim3(10,20,4), 256, 0, stream>>>(FUS, wsf, Y1);
    k_fc<<<NPIX/128, 128, 0, stream>>>(Y1, x, wsf, fc_b, out);
}

// Round 6
// 182.211 us; speedup vs baseline: 3.2095x; 1.2676x over previous
//
#include <hip/hip_runtime.h>
#include <hip/hip_bf16.h>
#include <math.h>

#define BB 4
#define CC 64
#define HH 160
#define WW 160
#define HWs (HH*WW)        // 25600
#define NPIX (BB*HWs)      // 102400

using bf16 = __hip_bfloat16;
typedef __attribute__((ext_vector_type(8))) short short8v;   // 8 x bf16 bits (4 VGPRs)
typedef __attribute__((ext_vector_type(4))) float float4v;   // MFMA accumulator

__device__ __forceinline__ unsigned short f2bfu(float f){
    union { bf16 h; unsigned short u; } cv; cv.h = __float2bfloat16(f); return cv.u;
}
__device__ __forceinline__ float bfu2f(unsigned short u){
    union { float f; unsigned int i; } cv; cv.i = ((unsigned int)u)<<16; return cv.f;
}

// ---- workspace layout (float offsets) ----
constexpr int B1X1 = 0;        // 64    : summed dyn1d biases (fp32)
constexpr int SFBo = 64;       // 64    : BN-folded sf bias (fp32)
constexpr int SFWf = 128;      // 18432 fl = 36864 bf16 : sf weights A-frag [og][tap][kc][lane][j]
constexpr int BAWf = 18560;    // 9216 fl = 18432 bf16  : ba_w1 A-frag [og][tap*2+kc][lane][j]
constexpr int FUWf = 27776;    // 2048 fl = 4096 bf16   : dyn1d 1x1 A-frag [wave][kc][lane][j]
constexpr int FCWf = 29824;    // 2048 fl = 4096 bf16   : fc A-frag [wave][kc][lane][j]
constexpr int WS_FLOATS = 31872;   // 127,488 B (16B aligned)
// bf16 NHWC region after: XB [p][c] then FUS [p][c], each NPIX*64 elems (13.1 MB)

// ================= K0: weight prep (folds + MFMA packs) =================
__global__ void k_prep(const float* __restrict__ rk5w, const float* __restrict__ rk5b,
                       const float* __restrict__ rk7w, const float* __restrict__ rk7b,
                       const float* __restrict__ lk5w, const float* __restrict__ lk5b,
                       const float* __restrict__ lk7w, const float* __restrict__ lk7b,
                       const float* __restrict__ sfw,  const float* __restrict__ sfb,
                       const float* __restrict__ bng,  const float* __restrict__ bnb,
                       const float* __restrict__ bnm,  const float* __restrict__ bnv,
                       const float* __restrict__ baw1, const float* __restrict__ fcw,
                       float* __restrict__ ws)
{
    int tid = blockIdx.x*blockDim.x + threadIdx.x;
    int nt  = gridDim.x*blockDim.x;
    // summed dyn1d biases
    for(int o=tid;o<64;o+=nt){
        int grp=o>>4, oo=o&15; int K=(grp&1)?7:5;
        const float* bp = (grp==0)?rk5b:(grp==1)?rk7b:(grp==2)?lk5b:lk7b;
        float s=0.f; for(int k=0;k<K;k++) s += bp[oo*K+k];
        ws[B1X1+o]=s;
    }
    // BN-folded sf bias
    for(int oc=tid;oc<64;oc+=nt){
        float sc = bng[oc]*rsqrtf(bnv[oc]+1e-5f);
        ws[SFBo+oc] = sfb[oc]*sc + bnb[oc] - bnm[oc]*sc;
    }
    // sf weights, BN-scaled, MFMA A-frag order: idx = og*9216 + tap*1024 + kc*512 + lane*8 + j
    unsigned short* sfwf = (unsigned short*)(ws + SFWf);
    for(int idx=tid; idx<36864; idx+=nt){
        int og = idx/9216;  int rem = idx - og*9216;
        int tp = rem/1024;  int rem2 = rem - tp*1024;
        int kc = rem2>>9;   int rem3 = rem2 & 511;
        int lane = rem3>>3; int j = rem3&7;
        int oc = og*16 + (lane&15);
        int ic = kc*32 + (lane>>4)*8 + j;
        float sc = bng[oc]*rsqrtf(bnv[oc]+1e-5f);
        sfwf[idx] = f2bfu(sfw[(oc*64+ic)*9 + tp] * sc);
    }
    // ba_w1 A-frag order: idx = ((og*18 + tap*2+kc)*64 + lane)*8 + j
    unsigned short* bawf = (unsigned short*)(ws + BAWf);
    for(int idx=tid; idx<18432; idx+=nt){
        int og = idx/9216;  int r1 = idx - og*9216;
        int f  = r1/512;    int r2 = r1 & 511;
        int lane = r2>>3;   int j = r2&7;
        int tap = f>>1, kc = f&1;
        int oc = og*16 + (lane&15);
        int ic = kc*32 + (lane>>4)*8 + j;
        bawf[idx] = f2bfu(baw1[(oc*64+ic)*9 + tap]);
    }
    // fused dyn1d 1x1 weights (k-summed), A-frag: idx = ((wave*2+kc)*64+lane)*8 + j
    unsigned short* fuwf = (unsigned short*)(ws + FUWf);
    for(int idx=tid; idx<4096; idx+=nt){
        int wave = idx>>10;
        int kc   = (idx>>9)&1;
        int lane = (idx>>3)&63;
        int j    = idx&7;
        int oc = wave*16 + (lane&15);
        int c  = kc*32 + (lane>>4)*8 + j;
        int oo = oc&15; int K = (wave&1)?7:5;
        const float* w = (wave==0)?rk5w:(wave==1)?rk7w:(wave==2)?lk5w:lk7w;
        float s = 0.f;
        for(int k=0;k<K;k++) s += w[(oo*K+k)*64 + c];
        fuwf[idx] = f2bfu(s);
    }
    // fc weights A-frag (same indexing)
    unsigned short* fcwf = (unsigned short*)(ws + FCWf);
    for(int idx=tid; idx<4096; idx+=nt){
        int wave = idx>>10;
        int kc   = (idx>>9)&1;
        int lane = (idx>>3)&63;
        int j    = idx&7;
        int oc = wave*16 + (lane&15);
        int c  = kc*32 + (lane>>4)*8 + j;
        fcwf[idx] = f2bfu(fcw[oc*64 + c]);
    }
}

// ============ K1: x (fp32 NCHW) -> XB (bf16 NHWC), swizzled LDS transpose ============
__global__ __launch_bounds__(256)
void k_x2nhwc(const float* __restrict__ x, unsigned short* __restrict__ xb)
{
    __shared__ unsigned short ls[128*72];    // 18.4 KB, XOR-swizzled 8-ch blocks
    const int t = threadIdx.x;
    const int p0 = blockIdx.x*128;
    const int b = p0 / HWs, pp0 = p0 % HWs;
    const float* xbase = x + (size_t)b*CC*HWs + pp0;
    #pragma unroll
    for(int iter=0; iter<32; iter++){
        int idx = iter*256 + t;
        int c = idx>>7, px = idx&127;
        int bs = (c>>3) ^ ((px>>3)&7);          // swizzle breaks bank ties
        ls[px*72 + bs*8 + (c&7)] = f2bfu(xbase[(size_t)c*HWs + px]);
    }
    __syncthreads();
    #pragma unroll
    for(int iter=0; iter<4; iter++){
        int idx = iter*256 + t;
        int sub = idx&7, px = idx>>3;
        int bs = sub ^ ((px>>3)&7);
        short8v v = *(short8v*)(ls + px*72 + bs*8);
        *(short8v*)(xb + ((size_t)(p0+px))*64 + sub*8) = v;
    }
}

// ====== K2: fused attn-conv + sobel + sigmoid + channel-sum + dyn1d -> FUS ======
// 16x8 px tile, 256 thr, 4 waves. z/A/sx never leave the block.
__global__ __launch_bounds__(256)
void k_fuseA(const unsigned short* __restrict__ xb, const float* __restrict__ bab1,
             const float* __restrict__ baw2, const float* __restrict__ bab2,
             const float* __restrict__ ws, unsigned short* __restrict__ fus)
{
    __shared__ unsigned short tile[10*18*72];  // 25,920 B
    __shared__ float zbuf[2][8][16];
    __shared__ float ebuf[2][128];
    __shared__ float sxbuf[8][16];
    __shared__ float pbuf[128], qbuf[128];
    const int bw = blockIdx.x, bh = blockIdx.y, b = blockIdx.z;
    const int t = threadIdx.x;
    const int wave = t>>6, lane = t&63;
    const int quad = lane>>4, n = lane&15;
    const int og = wave&1, rh = wave>>1;
    const int w0 = bw*16, h0 = bh*8;

    const unsigned short* fb = xb + (size_t)b*HWs*64;
    for(int idx=t; idx<1440; idx+=256){
        int sub = idx&7; int pix = idx>>3;
        int row = pix/18, col = pix%18;
        int gh = h0-1+row, gw = w0-1+col;
        short8v v = {0,0,0,0,0,0,0,0};
        if(gh>=0&&gh<HH&&gw>=0&&gw<WW)
            v = *(const short8v*)(fb + ((size_t)(gh*WW+gw))*64 + sub*8);
        *(short8v*)(tile + (row*18+col)*72 + sub*8) = v;
    }
    const unsigned short* bawf = (const unsigned short*)(ws + BAWf);
    short8v afrag[18];
    #pragma unroll
    for(int f=0; f<18; f++)
        afrag[f] = *(const short8v*)(bawf + (((size_t)og*18 + f)*64 + lane)*8);
    const unsigned short* fuwf = (const unsigned short*)(ws + FUWf);
    short8v wfrag[2];
    #pragma unroll
    for(int kc=0; kc<2; kc++)
        wfrag[kc] = *(const short8v*)(fuwf + (((size_t)wave*2 + kc)*64 + lane)*8);
    short8v ones;
    #pragma unroll
    for(int j=0;j<8;j++) ones[j] = (short)0x3F80;   // bf16 1.0
    float b1[4], w2[4], bq[4];
    #pragma unroll
    for(int r=0;r<4;r++){
        b1[r] = bab1[og*16 + quad*4 + r];
        w2[r] = baw2[og*16 + quad*4 + r];
        bq[r] = ws[B1X1 + wave*16 + quad*4 + r];
    }
    __syncthreads();

    // --- attn conv MFMA: wave covers rows rh*4..rh*4+3, oc group og ---
    #pragma unroll
    for(int srp=0; srp<2; srp++){
        const int gr0 = rh*4 + srp*2, gr1 = gr0+1;
        float4v acc0={0,0,0,0}, acc1={0,0,0,0};
        #pragma unroll
        for(int tap=0; tap<9; tap++){
            const int dh = tap/3, dw = tap%3;
            const unsigned short* base0 = tile + ((gr0+dh)*18 + dw + n)*72 + quad*8;
            const unsigned short* base1 = tile + ((gr1+dh)*18 + dw + n)*72 + quad*8;
            #pragma unroll
            for(int kc=0; kc<2; kc++){
                short8v v0 = *(const short8v*)(base0 + kc*32);
                short8v v1 = *(const short8v*)(base1 + kc*32);
                acc0 = __builtin_amdgcn_mfma_f32_16x16x32_bf16(afrag[tap*2+kc], v0, acc0, 0,0,0);
                acc1 = __builtin_amdgcn_mfma_f32_16x16x32_bf16(afrag[tap*2+kc], v1, acc1, 0,0,0);
            }
        }
        float c0 = 0.f, c1 = 0.f;
        #pragma unroll
        for(int r=0;r<4;r++){
            c0 += fmaxf(acc0[r] + b1[r], 0.f) * w2[r];
            c1 += fmaxf(acc1[r] + b1[r], 0.f) * w2[r];
        }
        c0 += __shfl_xor(c0, 16); c0 += __shfl_xor(c0, 32);
        c1 += __shfl_xor(c1, 16); c1 += __shfl_xor(c1, 32);
        if(lane < 16){
            zbuf[og][gr0][lane] = c0;
            zbuf[og][gr1][lane] = c1;
        }
    }

    // --- channel sums via ones-A MFMA: wave covers rows 2w, 2w+1 ---
    {
        const int r0 = wave*2, r1 = wave*2+1;
        float4v sa0={0,0,0,0}, sa1={0,0,0,0};
        #pragma unroll
        for(int kc=0; kc<2; kc++){
            short8v v0 = *(const short8v*)(tile + ((r0+1)*18 + 1 + n)*72 + quad*8 + kc*32);
            short8v v1 = *(const short8v*)(tile + ((r1+1)*18 + 1 + n)*72 + quad*8 + kc*32);
            sa0 = __builtin_amdgcn_mfma_f32_16x16x32_bf16(ones, v0, sa0, 0,0,0);
            sa1 = __builtin_amdgcn_mfma_f32_16x16x32_bf16(ones, v1, sa1, 0,0,0);
        }
        if(lane < 16){
            sxbuf[r0][lane] = sa0[0];
            sxbuf[r1][lane] = sa1[0];
        }
    }

    // --- Sobel edge from the same LDS tile ---
    {
        const int half = t>>7, px = t&127;
        const int r = px>>4, c = px&15;
        float e = 0.f;
        #pragma unroll
        for(int s=0; s<4; s++){
            const int sub = half*4 + s;
            if(half==0){
                short8v a0 = *(const short8v*)(tile + ((r  )*18 + c  )*72 + sub*8);
                short8v a2 = *(const short8v*)(tile + ((r  )*18 + c+2)*72 + sub*8);
                short8v a3 = *(const short8v*)(tile + ((r+1)*18 + c  )*72 + sub*8);
                short8v a5 = *(const short8v*)(tile + ((r+1)*18 + c+2)*72 + sub*8);
                short8v a6 = *(const short8v*)(tile + ((r+2)*18 + c  )*72 + sub*8);
                short8v a8 = *(const short8v*)(tile + ((r+2)*18 + c+2)*72 + sub*8);
                #pragma unroll
                for(int j=0;j<8;j++){
                    float gx = (bfu2f((unsigned short)a2[j]) - bfu2f((unsigned short)a0[j]))
                       + 2.f*(bfu2f((unsigned short)a5[j]) - bfu2f((unsigned short)a3[j]))
                       +      (bfu2f((unsigned short)a8[j]) - bfu2f((unsigned short)a6[j]));
                    e += fabsf(gx);
                }
            } else {
                short8v b0 = *(const short8v*)(tile + ((r  )*18 + c  )*72 + sub*8);
                short8v b1v= *(const short8v*)(tile + ((r  )*18 + c+1)*72 + sub*8);
                short8v b2 = *(const short8v*)(tile + ((r  )*18 + c+2)*72 + sub*8);
                short8v b6 = *(const short8v*)(tile + ((r+2)*18 + c  )*72 + sub*8);
                short8v b7 = *(const short8v*)(tile + ((r+2)*18 + c+1)*72 + sub*8);
                short8v b8 = *(const short8v*)(tile + ((r+2)*18 + c+2)*72 + sub*8);
                #pragma unroll
                for(int j=0;j<8;j++){
                    float gy = (bfu2f((unsigned short)b6[j]) - bfu2f((unsigned short)b0[j]))
                       + 2.f*(bfu2f((unsigned short)b7[j]) - bfu2f((unsigned short)b1v[j]))
                       +      (bfu2f((unsigned short)b8[j]) - bfu2f((unsigned short)b2[j]));
                    e += fabsf(gy);
                }
            }
        }
        ebuf[half][px] = e;
    }
    __syncthreads();

    // --- per-pixel scalars: A = 1+sigmoid(z), P = A^2*sx, Q = A*sx ---
    if(t < 128){
        const int row = t>>4, col = t&15;
        float z = zbuf[0][row][col] + zbuf[1][row][col] + bab2[0]
                + (ebuf[0][t] + ebuf[1][t]) * (1.f/32.f);
        float A = 1.f + 1.f/(1.f+__expf(-z));
        float S = A * sxbuf[row][col];
        pbuf[t] = A*S;
        qbuf[t] = S;
    }
    __syncthreads();

    // --- dyn1d 1x1 via MFMA: fus_o = P*dot_o + Q*b_o ---
    #pragma unroll
    for(int srp=0; srp<4; srp++){
        const int r0 = srp*2, r1 = srp*2+1;
        float4v acc0={0,0,0,0}, acc1={0,0,0,0};
        #pragma unroll
        for(int kc=0; kc<2; kc++){
            short8v v0 = *(const short8v*)(tile + ((r0+1)*18 + 1 + n)*72 + quad*8 + kc*32);
            short8v v1 = *(const short8v*)(tile + ((r1+1)*18 + 1 + n)*72 + quad*8 + kc*32);
            acc0 = __builtin_amdgcn_mfma_f32_16x16x32_bf16(wfrag[kc], v0, acc0, 0,0,0);
            acc1 = __builtin_amdgcn_mfma_f32_16x16x32_bf16(wfrag[kc], v1, acc1, 0,0,0);
        }
        union { unsigned long long u; unsigned short s[4]; } pk0, pk1;
        const int px0 = r0*16 + n, px1 = r1*16 + n;
        const float P0 = pbuf[px0], Q0 = qbuf[px0];
        const float P1 = pbuf[px1], Q1 = qbuf[px1];
        #pragma unroll
        for(int r=0;r<4;r++){
            pk0.s[r] = f2bfu(P0*acc0[r] + Q0*bq[r]);
            pk1.s[r] = f2bfu(P1*acc1[r] + Q1*bq[r]);
        }
        unsigned short* fp0 = fus + ((size_t)b*HWs + (h0+r0)*WW + w0 + n)*64 + wave*16 + quad*4;
        unsigned short* fp1 = fus + ((size_t)b*HWs + (h0+r1)*WW + w0 + n)*64 + wave*16 + quad*4;
        *(unsigned long long*)fp0 = pk0.u;
        *(unsigned long long*)fp1 = pk1.u;
    }
}

// ====== K3: fused sf 3x3 conv (MFMA) + ReLU + fc 1x1 (MFMA) + residual -> out ======
__global__ __launch_bounds__(256)
void k_fuseB(const unsigned short* __restrict__ fus, const float* __restrict__ ws,
             const float* __restrict__ fcb, const float* __restrict__ x,
             float* __restrict__ out)
{
    __shared__ unsigned short ftile[10*18*72];  // 25,920 B
    __shared__ unsigned short ytile[128*72];    // 18,432 B
    const int bw = blockIdx.x, bh = blockIdx.y, b = blockIdx.z;
    const int t  = threadIdx.x;
    const int wave = t>>6, lane = t&63;
    const int quad = lane>>4, n = lane&15;
    const int w0 = bw*16, h0 = bh*8;

    const unsigned short* fb = fus + (size_t)b*HWs*64;
    for(int idx=t; idx<1440; idx+=256){
        int sub = idx&7; int pix = idx>>3;
        int row = pix/18, col = pix%18;
        int gh = h0-1+row, gw = w0-1+col;
        short8v v = {0,0,0,0,0,0,0,0};
        if(gh>=0&&gh<HH&&gw>=0&&gw<WW)
            v = *(const short8v*)(fb + ((size_t)(gh*WW+gw))*64 + sub*8);
        *(short8v*)(ftile + (row*18+col)*72 + sub*8) = v;
    }
    const unsigned short* sfwf = (const unsigned short*)(ws + SFWf);
    short8v afrag[18];
    #pragma unroll
    for(int f=0; f<18; f++)
        afrag[f] = *(const short8v*)(sfwf + (((size_t)wave*18 + f)*64 + lane)*8);
    const unsigned short* fcwf = (const unsigned short*)(ws + FCWf);
    short8v ffrag[2];
    #pragma unroll
    for(int kc=0; kc<2; kc++)
        ffrag[kc] = *(const short8v*)(fcwf + (((size_t)wave*2 + kc)*64 + lane)*8);
    float bias[4], fb4[4];
    #pragma unroll
    for(int r=0;r<4;r++){
        bias[r] = ws[SFBo + wave*16 + quad*4 + r];
        fb4[r]  = fcb[wave*16 + quad*4 + r];
    }
    __syncthreads();

    // --- sf conv MFMA -> relu -> bf16 ytile ---
    #pragma unroll
    for(int srp=0; srp<4; srp++){
        const int r0 = srp*2, r1 = srp*2+1;
        float4v acc0={0,0,0,0}, acc1={0,0,0,0};
        #pragma unroll
        for(int tap=0; tap<9; tap++){
            const int dh = tap/3, dw = tap%3;
            const unsigned short* base0 = ftile + ((r0+dh)*18 + dw + n)*72 + quad*8;
            const unsigned short* base1 = ftile + ((r1+dh)*18 + dw + n)*72 + quad*8;
            #pragma unroll
            for(int kc=0; kc<2; kc++){
                short8v b0 = *(const short8v*)(base0 + kc*32);
                short8v b1 = *(const short8v*)(base1 + kc*32);
                acc0 = __builtin_amdgcn_mfma_f32_16x16x32_bf16(afrag[tap*2+kc], b0, acc0, 0,0,0);
                acc1 = __builtin_amdgcn_mfma_f32_16x16x32_bf16(afrag[tap*2+kc], b1, acc1, 0,0,0);
            }
        }
        union { unsigned long long u; unsigned short s[4]; } pk0, pk1;
        #pragma unroll
        for(int r=0;r<4;r++){
            pk0.s[r] = f2bfu(fmaxf(acc0[r] + bias[r], 0.f));
            pk1.s[r] = f2bfu(fmaxf(acc1[r] + bias[r], 0.f));
        }
        *(unsigned long long*)(ytile + (r0*16+n)*72 + wave*16 + quad*4) = pk0.u;
        *(unsigned long long*)(ytile + (r1*16+n)*72 + wave*16 + quad*4) = pk1.u;
    }
    __syncthreads();

    // --- fc 1x1 MFMA + bias + residual -> fp32 NCHW out ---
    #pragma unroll
    for(int srp=0; srp<4; srp++){
        const int r0 = srp*2, r1 = srp*2+1;
        float4v acc0={0,0,0,0}, acc1={0,0,0,0};
        #pragma unroll
        for(int kc=0; kc<2; kc++){
            short8v b0 = *(const short8v*)(ytile + (r0*16+n)*72 + quad*8 + kc*32);
            short8v b1 = *(const short8v*)(ytile + (r1*16+n)*72 + quad*8 + kc*32);
            acc0 = __builtin_amdgcn_mfma_f32_16x16x32_bf16(ffrag[kc], b0, acc0, 0,0,0);
            acc1 = __builtin_amdgcn_mfma_f32_16x16x32_bf16(ffrag[kc], b1, acc1, 0,0,0);
        }
        #pragma unroll
        for(int r=0;r<4;r++){
            int oc = wave*16 + quad*4 + r;
            size_t g0 = ((size_t)(b*CC + oc))*HWs + (h0+r0)*WW + w0 + n;
            size_t g1 = ((size_t)(b*CC + oc))*HWs + (h0+r1)*WW + w0 + n;
            out[g0] = acc0[r] + fb4[r] + x[g0];
            out[g1] = acc1[r] + fb4[r] + x[g1];
        }
    }
}

extern "C" void kernel_launch(void* const* d_in, const int* in_sizes, int n_in,
                              void* d_out, int out_size, void* d_ws, size_t ws_size,
                              hipStream_t stream)
{
    const float* x     = (const float*)d_in[0];
    const float* ba_w1 = (const float*)d_in[1];
    const float* ba_b1 = (const float*)d_in[2];
    const float* ba_w2 = (const float*)d_in[3];
    const float* ba_b2 = (const float*)d_in[4];
    // d_in[5..12] = offset branch: dead code in the reference (never reaches the output)
    const float* rk5_w = (const float*)d_in[13];
    const float* rk5_b = (const float*)d_in[14];
    const float* rk7_w = (const float*)d_in[15];
    const float* rk7_b = (const float*)d_in[16];
    const float* lk5_w = (const float*)d_in[17];
    const float* lk5_b = (const float*)d_in[18];
    const float* lk7_w = (const float*)d_in[19];
    const float* lk7_b = (const float*)d_in[20];
    const float* sf_w  = (const float*)d_in[21];
    const float* sf_b  = (const float*)d_in[22];
    const float* bng   = (const float*)d_in[23];
    const float* bnb   = (const float*)d_in[24];
    const float* bnm   = (const float*)d_in[25];
    const float* bnv   = (const float*)d_in[26];
    const float* fc_w  = (const float*)d_in[27];
    const float* fc_b  = (const float*)d_in[28];

    float* wsf = (float*)d_ws;
    unsigned short* XB  = (unsigned short*)((char*)d_ws + (size_t)WS_FLOATS*4);
    unsigned short* FUS = XB + (size_t)NPIX*64;
    float* out = (float*)d_out;

    k_prep<<<64, 256, 0, stream>>>(rk5_w,rk5_b,rk7_w,rk7_b,lk5_w,lk5_b,lk7_w,lk7_b,
                                   sf_w,sf_b,bng,bnb,bnm,bnv, ba_w1, fc_w, wsf);
    k_x2nhwc<<<NPIX/128, 256, 0, stream>>>(x, XB);
    k_fuseA<<<dim3(10,20,4), 256, 0, stream>>>(XB, ba_b1, ba_w2, ba_b2, wsf, FUS);
    k_fuseB<<<dim3(10,20,4), 256, 0, stream>>>(FUS, wsf, fc_b, x, out);
}